// Round 8
// baseline (787.676 us; speedup 1.0000x reference)
//
#include <hip/hip_runtime.h>
#include <stdint.h>

// ---------- types ----------
typedef __bf16  bf16x8 __attribute__((ext_vector_type(8)));
typedef float   f32x4  __attribute__((ext_vector_type(4)));
typedef float   f32x16 __attribute__((ext_vector_type(16)));
typedef uint32_t u32x4 __attribute__((ext_vector_type(4)));

__device__ inline short f2bf(float f) {
  union { float f; uint32_t u; } v; v.f = f;
  uint32_t r = v.u + 0x7FFFu + ((v.u >> 16) & 1u);   // RNE
  return (short)(r >> 16);
}

// B=4, H=W=D=16 -> N=4096 tokens/batch, C=512, GROUPS=32 (16 ch/group)

// ---------- GroupNorm stats: 256 blocks (full GPU), per-half partial sums ----------
__global__ __launch_bounds__(256) void gn_stats_k(const float* __restrict__ x,
                                                  float2* __restrict__ sums) {
  int bg2 = blockIdx.x;                       // (b,g,half): bg = bg2>>1
  int bg = bg2 >> 1, half = bg2 & 1;
  int b = bg >> 5, g = bg & 31;
  int tid = threadIdx.x;
  const float* base = x + (size_t)b * 4096 * 512 + (size_t)half * 2048 * 512 + g * 16;
  float s = 0.f, q = 0.f;
  for (int i = tid; i < 8192; i += 256) {
    int n = i >> 2, sub = i & 3;
    float4 v = *(const float4*)(base + (size_t)n * 512 + sub * 4);
    s += v.x + v.y + v.z + v.w;
    q += v.x * v.x + v.y * v.y + v.z * v.z + v.w * v.w;
  }
  for (int off = 32; off > 0; off >>= 1) {
    s += __shfl_down(s, off, 64);
    q += __shfl_down(q, off, 64);
  }
  __shared__ float rs[4], rq[4];
  int w = tid >> 6;
  if ((tid & 63) == 0) { rs[w] = s; rq[w] = q; }
  __syncthreads();
  if (tid == 0) {
    float2 o;
    o.x = rs[0] + rs[1] + rs[2] + rs[3];
    o.y = rq[0] + rq[1] + rq[2] + rq[3];
    sums[bg2] = o;
  }
}

// ---------- GN apply -> bf16 h (derives mean/rstd from partial sums) ----------
__global__ __launch_bounds__(256) void gn_apply_k(const float* __restrict__ x,
                                                  const float2* __restrict__ sums,
                                                  const float* __restrict__ sc,
                                                  const float* __restrict__ bi,
                                                  short* __restrict__ h) {
  size_t i4 = ((size_t)blockIdx.x * 256 + threadIdx.x) * 4;
  int c = (int)(i4 & 511);
  int tok = (int)(i4 >> 9);
  int b = tok >> 12;
  int bg = b * 32 + (c >> 4);
  float2 p0 = sums[bg * 2], p1 = sums[bg * 2 + 1];
  float m = (p0.x + p1.x) * (1.f / 65536.f);
  float var = (p0.y + p1.y) * (1.f / 65536.f) - m * m;
  float r = rsqrtf(var + 1e-6f);
  float4 v = *(const float4*)(x + i4);
  float4 s = *(const float4*)(sc + c);
  float4 bb = *(const float4*)(bi + c);
  short4 o;
  o.x = f2bf((v.x - m) * r * s.x + bb.x);
  o.y = f2bf((v.y - m) * r * s.y + bb.y);
  o.z = f2bf((v.z - m) * r * s.z + bb.z);
  o.w = f2bf((v.w - m) * r * s.w + bb.w);
  *(short4*)(h + i4) = o;
}

// ---------- weights -> bf16, transposed ----------
__global__ __launch_bounds__(256) void wconv_k(const float* __restrict__ wq,
                                               const float* __restrict__ wk,
                                               const float* __restrict__ wv,
                                               const float* __restrict__ wp,
                                               short* __restrict__ wt) {
  int i = blockIdx.x * 256 + threadIdx.x;
  int widx = i >> 18, rem = i & 262143;
  int c = rem >> 9, j = rem & 511;
  const float* w = widx == 0 ? wq : widx == 1 ? wk : widx == 2 ? wv : wp;
  wt[(size_t)widx * 262144 + (size_t)j * 512 + c] = f2bf(w[(size_t)c * 512 + j]);
}

// ---------- fused Q/K/V GEMM: one dispatch, grid (128, 12) ----------
__global__ __launch_bounds__(256) void qkv_gemm_k(const short* __restrict__ A,
                                                  const short* __restrict__ wt,
                                                  const float* __restrict__ bq,
                                                  const float* __restrict__ bk,
                                                  const float* __restrict__ bv,
                                                  short* __restrict__ Qb,
                                                  short* __restrict__ Kb,
                                                  short* __restrict__ Vt) {
  __shared__ __attribute__((aligned(16))) short As[128 * 32];
  __shared__ __attribute__((aligned(16))) short Bs[128 * 32];
  int widx = blockIdx.y >> 2;
  int n0 = (blockIdx.y & 3) * 128;
  const short* Bt = wt + (size_t)widx * 262144;
  const float* bias = widx == 0 ? bq : widx == 1 ? bk : bv;
  const float qscale = widx == 0 ? 0.06375872f : 1.0f;   // 512^-0.5 * log2(e)

  int tid = threadIdx.x;
  int w = tid >> 6, lane = tid & 63, quad = lane >> 4, mrow = lane & 15;
  int wm = w >> 1, wn = w & 1;
  int m0 = blockIdx.x * 128;

  const f32x4 fz = {0.f, 0.f, 0.f, 0.f};
  f32x4 acc[4][4];
#pragma unroll
  for (int i = 0; i < 4; i++)
#pragma unroll
    for (int j = 0; j < 4; j++) acc[i][j] = fz;

  int srow = tid >> 2;
  int scol = (tid & 3) * 8;

  for (int k0 = 0; k0 < 512; k0 += 32) {
    __syncthreads();
#pragma unroll
    for (int i = 0; i < 2; i++) {
      const short* ga = A + (size_t)(m0 + i * 64 + srow) * 512 + k0 + scol;
      const short* gb = Bt + (size_t)(n0 + i * 64 + srow) * 512 + k0 + scol;
      char* la = (char*)As + i * 4096 + w * 1024;
      char* lb = (char*)Bs + i * 4096 + w * 1024;
      __builtin_amdgcn_global_load_lds((__attribute__((address_space(1))) void*)ga,
                                       (__attribute__((address_space(3))) void*)la, 16, 0, 0);
      __builtin_amdgcn_global_load_lds((__attribute__((address_space(1))) void*)gb,
                                       (__attribute__((address_space(3))) void*)lb, 16, 0, 0);
    }
    __syncthreads();
    bf16x8 af[4], bfv[4];
#pragma unroll
    for (int mi = 0; mi < 4; mi++)
      af[mi] = *(const bf16x8*)&As[(wm * 64 + mi * 16 + mrow) * 32 + quad * 8];
#pragma unroll
    for (int ni = 0; ni < 4; ni++)
      bfv[ni] = *(const bf16x8*)&Bs[(wn * 64 + ni * 16 + mrow) * 32 + quad * 8];
#pragma unroll
    for (int mi = 0; mi < 4; mi++)
#pragma unroll
      for (int ni = 0; ni < 4; ni++)
        acc[mi][ni] = __builtin_amdgcn_mfma_f32_16x16x32_bf16(af[mi], bfv[ni], acc[mi][ni], 0, 0, 0);
  }

#pragma unroll
  for (int mi = 0; mi < 4; mi++)
#pragma unroll
    for (int ni = 0; ni < 4; ni++) {
      int col = n0 + wn * 64 + ni * 16 + mrow;
      float bv2 = bias[col];
      if (widx < 2) {
        short* outb = widx ? Kb : Qb;
#pragma unroll
        for (int r = 0; r < 4; r++) {
          int row = m0 + wm * 64 + mi * 16 + quad * 4 + r;
          outb[(size_t)row * 512 + col] = f2bf((acc[mi][ni][r] + bv2) * qscale);
        }
      } else {
        int row0 = m0 + wm * 64 + mi * 16 + quad * 4;
        int b = row0 >> 12, t0 = row0 & 4095;
        short4 o;
        o.x = f2bf(acc[mi][ni][0] + bv2);
        o.y = f2bf(acc[mi][ni][1] + bv2);
        o.z = f2bf(acc[mi][ni][2] + bv2);
        o.w = f2bf(acc[mi][ni][3] + bv2);
        *(short4*)&Vt[(size_t)b * (512 * 4096) + (size_t)col * 4096 + t0] = o;
      }
    }
}

// ---------- GEMM (final projection, validated) ----------
__global__ __launch_bounds__(256) void gemm_k(const short* __restrict__ A,
                                              const short* __restrict__ Bt,
                                              const float* __restrict__ bias,
                                              const float* __restrict__ xres,
                                              float* __restrict__ outf) {
  __shared__ __attribute__((aligned(16))) short As[128 * 32];
  __shared__ __attribute__((aligned(16))) short Bs[128 * 32];
  int tid = threadIdx.x;
  int w = tid >> 6, lane = tid & 63, quad = lane >> 4, mrow = lane & 15;
  int wm = w >> 1, wn = w & 1;
  int m0 = blockIdx.x * 128, n0 = blockIdx.y * 128;

  const f32x4 fz = {0.f, 0.f, 0.f, 0.f};
  f32x4 acc[4][4];
#pragma unroll
  for (int i = 0; i < 4; i++)
#pragma unroll
    for (int j = 0; j < 4; j++) acc[i][j] = fz;

  int srow = tid >> 2;
  int scol = (tid & 3) * 8;

  for (int k0 = 0; k0 < 512; k0 += 32) {
    __syncthreads();
#pragma unroll
    for (int i = 0; i < 2; i++) {
      const short* ga = A + (size_t)(m0 + i * 64 + srow) * 512 + k0 + scol;
      const short* gb = Bt + (size_t)(n0 + i * 64 + srow) * 512 + k0 + scol;
      char* la = (char*)As + i * 4096 + w * 1024;
      char* lb = (char*)Bs + i * 4096 + w * 1024;
      __builtin_amdgcn_global_load_lds((__attribute__((address_space(1))) void*)ga,
                                       (__attribute__((address_space(3))) void*)la, 16, 0, 0);
      __builtin_amdgcn_global_load_lds((__attribute__((address_space(1))) void*)gb,
                                       (__attribute__((address_space(3))) void*)lb, 16, 0, 0);
    }
    __syncthreads();
    bf16x8 af[4], bfv[4];
#pragma unroll
    for (int mi = 0; mi < 4; mi++)
      af[mi] = *(const bf16x8*)&As[(wm * 64 + mi * 16 + mrow) * 32 + quad * 8];
#pragma unroll
    for (int ni = 0; ni < 4; ni++)
      bfv[ni] = *(const bf16x8*)&Bs[(wn * 64 + ni * 16 + mrow) * 32 + quad * 8];
#pragma unroll
    for (int mi = 0; mi < 4; mi++)
#pragma unroll
      for (int ni = 0; ni < 4; ni++)
        acc[mi][ni] = __builtin_amdgcn_mfma_f32_16x16x32_bf16(af[mi], bfv[ni], acc[mi][ni], 0, 0, 0);
  }

#pragma unroll
  for (int mi = 0; mi < 4; mi++)
#pragma unroll
    for (int ni = 0; ni < 4; ni++) {
      int col = n0 + wn * 64 + ni * 16 + mrow;
      float bv = bias[col];
#pragma unroll
      for (int r = 0; r < 4; r++) {
        int row = m0 + wm * 64 + mi * 16 + quad * 4 + r;
        size_t idx = (size_t)row * 512 + col;
        outf[idx] = xres[idx] + acc[mi][ni][r] + bv;
      }
    }
}

// ---------- flash attention v14: v13 + cross-iteration software pipeline ----------
// v13 (411us): within an iter, softmax VALU serializes behind QK MFMA + the
// Sx write->lgkmcnt->barrier->read round trip. v14 pipelines by ONE iter:
// body(it) = { QK(it+1) -> Sx write(it+1) } || { Sx read(it) -> softmax(it)
// -> pack -> PV(it) } -- two INDEPENDENT dep chains (matrix pipe vs VALU),
// scheduler interleaves; the Sx round trip gets a whole body of slack.
// Own S-partial is read BACK from Sx (+4 ds_reads) instead of held across the
// barrier (-32 VGPR) -> peak ~240 VGPR, 2 waves/SIMD. V double-state vrA/vrB
// swapped positionally (static indexing); template<int C> keeps LDS buffers
// static. vmcnt(8) discipline as v13 (staging issued before V loads).
__device__ __forceinline__ f32x16 qkmfma(bf16x8 a, bf16x8 b, f32x16 c) {
  return __builtin_amdgcn_mfma_f32_32x32x16_bf16(a, b, c, 0, 0, 0);
}

template <int C>
__device__ __forceinline__ void fbody(int it,
                                      const short* __restrict__ K,
                                      const short* __restrict__ Vb0,
                                      short (&Ks)[2][16384], float (&Sx)[2][8192],
                                      const bf16x8 (&qf)[16], f32x16 (&oacc)[4],
                                      bf16x8 (&vrC)[4][2], bf16x8 (&vrN)[4][2],
                                      float& mrun, float& lrun,
                                      size_t batch_off, int w, int lane,
                                      int ql, int hi, int kj) {
  const f32x16 fz16 = {0,0,0,0,0,0,0,0,0,0,0,0,0,0,0,0};
  const int t1 = it + 1, t2 = it + 2;
  // 1. stage K(t2) -> Ks[C] (last read by QK(it) in previous body, pre-barrier)
  if (t2 < 128) {
#pragma unroll
    for (int i = 0; i < 4; i++) {
      int s = w * 4 + i;
      const short* gk = K + batch_off + (size_t)(t2 * 32 + ql) * 512 + s * 16 + hi * 8;
      __builtin_amdgcn_global_load_lds((__attribute__((address_space(1))) void*)gk,
                                       (__attribute__((address_space(3))) void*)&Ks[C][s * 512],
                                       16, 0, 0);
    }
  }
  asm volatile("" ::: "memory");              // staging precedes V loads in vmem order
  // 2. V loads(t1) -> vrN (consumed next body; huge latency window)
  if (t1 < 128) {
#pragma unroll
    for (int cb = 0; cb < 4; cb++) {
      vrN[cb][0] = *(const bf16x8*)(Vb0 + (size_t)cb * 131072 + t1 * 32);
      vrN[cb][1] = *(const bf16x8*)(Vb0 + (size_t)cb * 131072 + t1 * 32 + 16);
    }
  }
  // 3. QK(t1): ds_read Ks[C^1] + MFMA, 2 chains (matrix-pipe chain)
  f32x16 s0 = fz16, s1 = fz16;
  if (t1 < 128) {
#pragma unroll
    for (int s = 0; s < 16; s += 2) {
      bf16x8 k0 = *(const bf16x8*)&Ks[C ^ 1][(kj * 16 + s + 0) * 512 + lane * 8];
      bf16x8 k1 = *(const bf16x8*)&Ks[C ^ 1][(kj * 16 + s + 1) * 512 + lane * 8];
      s0 = qkmfma(k0, qf[s + 0], s0);
      s1 = qkmfma(k1, qf[s + 1], s1);
    }
  }
  // 4. softmax(it): read own + partner partials from Sx[C] (VALU chain,
  //    independent of #3 -- interleaves under the MFMA/ds latency)
  float pl[16];
#pragma unroll
  for (int i = 0; i < 4; i++) {
    f32x4 a = *(const f32x4*)&Sx[C][w * 1024 + i * 256 + lane * 4];
    f32x4 d = *(const f32x4*)&Sx[C][(w ^ 2) * 1024 + i * 256 + lane * 4];
    pl[4 * i + 0] = a[0] + d[0];
    pl[4 * i + 1] = a[1] + d[1];
    pl[4 * i + 2] = a[2] + d[2];
    pl[4 * i + 3] = a[3] + d[3];
  }
  float mx = pl[0];
#pragma unroll
  for (int r = 1; r < 16; r++) mx = fmaxf(mx, pl[r]);
  mx = fmaxf(mx, __shfl_xor(mx, 32, 64));
  if (__any(mx > mrun + 8.0f)) {              // defer-max (THR=8, validated)
    float mn = fmaxf(mrun, mx);
    float alpha = exp2f(mrun - mn);
    mrun = mn;
    lrun *= alpha;
    float al[16];
#pragma unroll
    for (int r = 0; r < 16; r++)
      al[r] = __shfl(alpha, (r & 3) + 8 * (r >> 2) + 4 * hi, 64);
#pragma unroll
    for (int cb = 0; cb < 4; cb++)
#pragma unroll
      for (int r = 0; r < 16; r++) oacc[cb][r] *= al[r];
  }
  float p[16];
  float sum = 0.f;
#pragma unroll
  for (int r = 0; r < 16; r++) {
    p[r] = exp2f(pl[r] - mrun);
    sum += p[r];
  }
  sum += __shfl_xor(sum, 32, 64);
  lrun += sum;
  // pack P -> A-frags (cvt_pk + word shfl_xor; v10/v13-validated)
  bf16x8 af0, af1;
#pragma unroll
  for (int ks = 0; ks < 2; ks++) {
    uint32_t Aw, Bw, Cw, Dw;
    asm("v_cvt_pk_bf16_f32 %0, %1, %2" : "=v"(Aw) : "v"(p[8 * ks + 0]), "v"(p[8 * ks + 1]));
    asm("v_cvt_pk_bf16_f32 %0, %1, %2" : "=v"(Bw) : "v"(p[8 * ks + 2]), "v"(p[8 * ks + 3]));
    asm("v_cvt_pk_bf16_f32 %0, %1, %2" : "=v"(Cw) : "v"(p[8 * ks + 4]), "v"(p[8 * ks + 5]));
    asm("v_cvt_pk_bf16_f32 %0, %1, %2" : "=v"(Dw) : "v"(p[8 * ks + 6]), "v"(p[8 * ks + 7]));
    uint32_t Asw = (uint32_t)__shfl_xor((int)Aw, 32, 64);
    uint32_t Bsw = (uint32_t)__shfl_xor((int)Bw, 32, 64);
    uint32_t Csw = (uint32_t)__shfl_xor((int)Cw, 32, 64);
    uint32_t Dsw = (uint32_t)__shfl_xor((int)Dw, 32, 64);
    u32x4 u;
    u[0] = hi ? Csw : Aw;
    u[1] = hi ? Dsw : Bw;
    u[2] = hi ? Cw : Asw;
    u[3] = hi ? Dw : Bsw;
    if (ks == 0) af0 = __builtin_bit_cast(bf16x8, u);
    else         af1 = __builtin_bit_cast(bf16x8, u);
  }
  // 5. PV(it) with vrC (loaded last body)
#pragma unroll
  for (int cb = 0; cb < 4; cb++) {
    oacc[cb] = qkmfma(af0, vrC[cb][0], oacc[cb]);
    oacc[cb] = qkmfma(af1, vrC[cb][1], oacc[cb]);
  }
  // 6. Sx[C^1] write of this body's QK partials (read after next barrier)
  if (t1 < 128) {
#pragma unroll
    for (int i = 0; i < 4; i++) {
      f32x4 cc;
      cc[0] = s0[4 * i + 0] + s1[4 * i + 0];
      cc[1] = s0[4 * i + 1] + s1[4 * i + 1];
      cc[2] = s0[4 * i + 2] + s1[4 * i + 2];
      cc[3] = s0[4 * i + 3] + s1[4 * i + 3];
      *(f32x4*)&Sx[C ^ 1][w * 1024 + i * 256 + lane * 4] = cc;
    }
  }
  // 7. THE barrier: Sx writes visible (lgkm), K staging landed (vmcnt<=8 = V)
  asm volatile("s_waitcnt lgkmcnt(0) vmcnt(8)" ::: "memory");
  __builtin_amdgcn_s_barrier();
  asm volatile("" ::: "memory");
}

__global__ __launch_bounds__(512, 2) void flash_k(const short* __restrict__ Q,
                                                  const short* __restrict__ K,
                                                  const short* __restrict__ Vt,
                                                  short* __restrict__ O) {
  __shared__ __attribute__((aligned(16))) short Ks[2][16384];   // 64 KB
  __shared__ __attribute__((aligned(16))) float Sx[2][8192];    // 64 KB exchange (dbuf)
  int L = blockIdx.x;
  int b = (L & 7) >> 1;                       // batch -> XCD pair (L%8 round-robin)
  int q0 = (((L >> 3) << 1) | (L & 1)) * 64;
  int tid = threadIdx.x;
  int w = tid >> 6, lane = tid & 63;
  int ql = lane & 31, hi = lane >> 5;
  int qh = w & 1;                             // query half (32 queries)
  int gg = w >> 1;                            // PV channel quarter (128 ch)
  int kj = gg & 1;                            // QK k-split half (256 ch)
  const size_t batch_off = (size_t)b * 4096 * 512;

  // Q fragments (B-operand 32x32x16: col=query=ql, k=hi*8+j); Q pre-scaled
  const short* Qrow = Q + batch_off + (size_t)(q0 + qh * 32 + ql) * 512 + kj * 256;
  bf16x8 qf[16];
#pragma unroll
  for (int s = 0; s < 16; s++)
    qf[s] = *(const bf16x8*)&Qrow[s * 16 + hi * 8];

  const f32x16 fz16 = {0,0,0,0,0,0,0,0,0,0,0,0,0,0,0,0};
  f32x16 oacc[4];
#pragma unroll
  for (int i = 0; i < 4; i++) oacc[i] = fz16;
  float mrun = -1e30f, lrun = 0.f;

  const short* Vb0 = Vt + batch_off + (size_t)(gg * 128 + ql) * 4096 + hi * 8;
  bf16x8 vrA[4][2], vrB[4][2];

  // ---- prologue: stage K(0); drain; stage K(1); V(0); QK(0); Sx[0]; barrier ----
#pragma unroll
  for (int i = 0; i < 4; i++) {
    int s = w * 4 + i;
    const short* gk = K + batch_off + (size_t)ql * 512 + s * 16 + hi * 8;
    __builtin_amdgcn_global_load_lds((__attribute__((address_space(1))) void*)gk,
                                     (__attribute__((address_space(3))) void*)&Ks[0][s * 512],
                                     16, 0, 0);
  }
  __syncthreads();                            // one-time full drain (K(0) ready)
#pragma unroll
  for (int i = 0; i < 4; i++) {
    int s = w * 4 + i;
    const short* gk = K + batch_off + (size_t)(32 + ql) * 512 + s * 16 + hi * 8;
    __builtin_amdgcn_global_load_lds((__attribute__((address_space(1))) void*)gk,
                                     (__attribute__((address_space(3))) void*)&Ks[1][s * 512],
                                     16, 0, 0);
  }
  asm volatile("" ::: "memory");
#pragma unroll
  for (int cb = 0; cb < 4; cb++) {
    vrA[cb][0] = *(const bf16x8*)(Vb0 + (size_t)cb * 131072);
    vrA[cb][1] = *(const bf16x8*)(Vb0 + (size_t)cb * 131072 + 16);
  }
  {
    f32x16 s0 = fz16, s1 = fz16;
#pragma unroll
    for (int s = 0; s < 16; s += 2) {
      bf16x8 k0 = *(const bf16x8*)&Ks[0][(kj * 16 + s + 0) * 512 + lane * 8];
      bf16x8 k1 = *(const bf16x8*)&Ks[0][(kj * 16 + s + 1) * 512 + lane * 8];
      s0 = qkmfma(k0, qf[s + 0], s0);
      s1 = qkmfma(k1, qf[s + 1], s1);
    }
#pragma unroll
    for (int i = 0; i < 4; i++) {
      f32x4 cc;
      cc[0] = s0[4 * i + 0] + s1[4 * i + 0];
      cc[1] = s0[4 * i + 1] + s1[4 * i + 1];
      cc[2] = s0[4 * i + 2] + s1[4 * i + 2];
      cc[3] = s0[4 * i + 3] + s1[4 * i + 3];
      *(f32x4*)&Sx[0][w * 1024 + i * 256 + lane * 4] = cc;
    }
  }
  asm volatile("s_waitcnt lgkmcnt(0) vmcnt(8)" ::: "memory");
  __builtin_amdgcn_s_barrier();
  asm volatile("" ::: "memory");

  // ---- pipelined main loop: two bodies per trip (static buffers/registers) ----
#pragma unroll 1
  for (int it2 = 0; it2 < 128; it2 += 2) {
    fbody<0>(it2,     K, Vb0, Ks, Sx, qf, oacc, vrA, vrB, mrun, lrun, batch_off, w, lane, ql, hi, kj);
    fbody<1>(it2 + 1, K, Vb0, Ks, Sx, qf, oacc, vrB, vrA, mrun, lrun, batch_off, w, lane, ql, hi, kj);
  }

  // ---- epilogue: O /= l, store bf16 row-major (rows=queries crow(r,hi)) ----
  float invl = 1.f / lrun;
  float ir[16];
#pragma unroll
  for (int r = 0; r < 16; r++)
    ir[r] = __shfl(invl, (r & 3) + 8 * (r >> 2) + 4 * hi, 64);
#pragma unroll
  for (int cb = 0; cb < 4; cb++) {
    int col = gg * 128 + cb * 32 + ql;
#pragma unroll
    for (int r = 0; r < 16; r++) {
      int row = q0 + qh * 32 + (r & 3) + 8 * (r >> 2) + 4 * hi;
      O[batch_off + (size_t)row * 512 + col] = f2bf(oacc[cb][r] * ir[r]);
    }
  }
}

extern "C" void kernel_launch(void* const* d_in, const int* in_sizes, int n_in,
                              void* d_out, int out_size, void* d_ws, size_t ws_size,
                              hipStream_t stream) {
  const float* x  = (const float*)d_in[0];
  const float* gs = (const float*)d_in[1];
  const float* gb = (const float*)d_in[2];
  const float* wq = (const float*)d_in[3];
  const float* bq = (const float*)d_in[4];
  const float* wk = (const float*)d_in[5];
  const float* bk = (const float*)d_in[6];
  const float* wv = (const float*)d_in[7];
  const float* bv = (const float*)d_in[8];
  const float* wp = (const float*)d_in[9];
  const float* bp = (const float*)d_in[10];
  float* out = (float*)d_out;

  // ---- workspace layout (~35.7 MB; Q/K live in d_out until final GEMM) ----
  char* ws = (char*)d_ws;
  float2* sums = (float2*)ws;                             // 256 float2 (2 KB)
  short* h    = (short*)(ws + 4096);                      // 16384*512 bf16 (16.78 MB)
  short* wt   = (short*)(ws + 4096 + 16777216);           // 4*512*512 bf16 (2 MB)
  short* Vt   = (short*)(ws + 4096 + 16777216 + 2097152); // [b][c][t] bf16 (16.78 MB)
  short* Qb   = (short*)d_out;                            // 16.78 MB in d_out
  short* Kb   = Qb + 8388608;                             // 16.78 MB in d_out
  short* Ob   = h;                                        // alias: h dead after V GEMM

  gn_stats_k<<<256, 256, 0, stream>>>(x, sums);
  gn_apply_k<<<8192, 256, 0, stream>>>(x, sums, gs, gb, h);
  wconv_k<<<4096, 256, 0, stream>>>(wq, wk, wv, wp, wt);
  qkv_gemm_k<<<dim3(128, 12), 256, 0, stream>>>(h, wt, bq, bk, bv, Qb, Kb, Vt);
  flash_k<<<256, 512, 0, stream>>>(Qb, Kb, Vt, Ob);
  // final projection reads Ob (=h space), x, wt_p; writes d_out (overwrites Q/K)
  gemm_k<<<dim3(128, 4), 256, 0, stream>>>(Ob, wt + 786432, bp, x, out);
}

// Round 9
// 635.688 us; speedup vs baseline: 1.2391x; 1.2391x over previous
//
#include <hip/hip_runtime.h>
#include <stdint.h>

// ---------- types ----------
typedef __bf16  bf16x8 __attribute__((ext_vector_type(8)));
typedef float   f32x4  __attribute__((ext_vector_type(4)));
typedef float   f32x16 __attribute__((ext_vector_type(16)));
typedef uint32_t u32x4 __attribute__((ext_vector_type(4)));

__device__ inline short f2bf(float f) {
  union { float f; uint32_t u; } v; v.f = f;
  uint32_t r = v.u + 0x7FFFu + ((v.u >> 16) & 1u);   // RNE
  return (short)(r >> 16);
}

// B=4, H=W=D=16 -> N=4096 tokens/batch, C=512, GROUPS=32 (16 ch/group)

// ---------- GroupNorm stats: 256 blocks (full GPU), per-half partial sums ----------
__global__ __launch_bounds__(256) void gn_stats_k(const float* __restrict__ x,
                                                  float2* __restrict__ sums) {
  int bg2 = blockIdx.x;                       // (b,g,half): bg = bg2>>1
  int bg = bg2 >> 1, half = bg2 & 1;
  int b = bg >> 5, g = bg & 31;
  int tid = threadIdx.x;
  const float* base = x + (size_t)b * 4096 * 512 + (size_t)half * 2048 * 512 + g * 16;
  float s = 0.f, q = 0.f;
  for (int i = tid; i < 8192; i += 256) {
    int n = i >> 2, sub = i & 3;
    float4 v = *(const float4*)(base + (size_t)n * 512 + sub * 4);
    s += v.x + v.y + v.z + v.w;
    q += v.x * v.x + v.y * v.y + v.z * v.z + v.w * v.w;
  }
  for (int off = 32; off > 0; off >>= 1) {
    s += __shfl_down(s, off, 64);
    q += __shfl_down(q, off, 64);
  }
  __shared__ float rs[4], rq[4];
  int w = tid >> 6;
  if ((tid & 63) == 0) { rs[w] = s; rq[w] = q; }
  __syncthreads();
  if (tid == 0) {
    float2 o;
    o.x = rs[0] + rs[1] + rs[2] + rs[3];
    o.y = rq[0] + rq[1] + rq[2] + rq[3];
    sums[bg2] = o;
  }
}

// ---------- GN apply -> bf16 h (derives mean/rstd from partial sums) ----------
__global__ __launch_bounds__(256) void gn_apply_k(const float* __restrict__ x,
                                                  const float2* __restrict__ sums,
                                                  const float* __restrict__ sc,
                                                  const float* __restrict__ bi,
                                                  short* __restrict__ h) {
  size_t i4 = ((size_t)blockIdx.x * 256 + threadIdx.x) * 4;
  int c = (int)(i4 & 511);
  int tok = (int)(i4 >> 9);
  int b = tok >> 12;
  int bg = b * 32 + (c >> 4);
  float2 p0 = sums[bg * 2], p1 = sums[bg * 2 + 1];
  float m = (p0.x + p1.x) * (1.f / 65536.f);
  float var = (p0.y + p1.y) * (1.f / 65536.f) - m * m;
  float r = rsqrtf(var + 1e-6f);
  float4 v = *(const float4*)(x + i4);
  float4 s = *(const float4*)(sc + c);
  float4 bb = *(const float4*)(bi + c);
  short4 o;
  o.x = f2bf((v.x - m) * r * s.x + bb.x);
  o.y = f2bf((v.y - m) * r * s.y + bb.y);
  o.z = f2bf((v.z - m) * r * s.z + bb.z);
  o.w = f2bf((v.w - m) * r * s.w + bb.w);
  *(short4*)(h + i4) = o;
}

// ---------- weights -> bf16, transposed ----------
__global__ __launch_bounds__(256) void wconv_k(const float* __restrict__ wq,
                                               const float* __restrict__ wk,
                                               const float* __restrict__ wv,
                                               const float* __restrict__ wp,
                                               short* __restrict__ wt) {
  int i = blockIdx.x * 256 + threadIdx.x;
  int widx = i >> 18, rem = i & 262143;
  int c = rem >> 9, j = rem & 511;
  const float* w = widx == 0 ? wq : widx == 1 ? wk : widx == 2 ? wv : wp;
  wt[(size_t)widx * 262144 + (size_t)j * 512 + c] = f2bf(w[(size_t)c * 512 + j]);
}

// ---------- fused Q/K/V GEMM: one dispatch, grid (128, 12) ----------
__global__ __launch_bounds__(256) void qkv_gemm_k(const short* __restrict__ A,
                                                  const short* __restrict__ wt,
                                                  const float* __restrict__ bq,
                                                  const float* __restrict__ bk,
                                                  const float* __restrict__ bv,
                                                  short* __restrict__ Qb,
                                                  short* __restrict__ Kb,
                                                  short* __restrict__ Vt) {
  __shared__ __attribute__((aligned(16))) short As[128 * 32];
  __shared__ __attribute__((aligned(16))) short Bs[128 * 32];
  int widx = blockIdx.y >> 2;
  int n0 = (blockIdx.y & 3) * 128;
  const short* Bt = wt + (size_t)widx * 262144;
  const float* bias = widx == 0 ? bq : widx == 1 ? bk : bv;
  const float qscale = widx == 0 ? 0.06375872f : 1.0f;   // 512^-0.5 * log2(e)

  int tid = threadIdx.x;
  int w = tid >> 6, lane = tid & 63, quad = lane >> 4, mrow = lane & 15;
  int wm = w >> 1, wn = w & 1;
  int m0 = blockIdx.x * 128;

  const f32x4 fz = {0.f, 0.f, 0.f, 0.f};
  f32x4 acc[4][4];
#pragma unroll
  for (int i = 0; i < 4; i++)
#pragma unroll
    for (int j = 0; j < 4; j++) acc[i][j] = fz;

  int srow = tid >> 2;
  int scol = (tid & 3) * 8;

  for (int k0 = 0; k0 < 512; k0 += 32) {
    __syncthreads();
#pragma unroll
    for (int i = 0; i < 2; i++) {
      const short* ga = A + (size_t)(m0 + i * 64 + srow) * 512 + k0 + scol;
      const short* gb = Bt + (size_t)(n0 + i * 64 + srow) * 512 + k0 + scol;
      char* la = (char*)As + i * 4096 + w * 1024;
      char* lb = (char*)Bs + i * 4096 + w * 1024;
      __builtin_amdgcn_global_load_lds((__attribute__((address_space(1))) void*)ga,
                                       (__attribute__((address_space(3))) void*)la, 16, 0, 0);
      __builtin_amdgcn_global_load_lds((__attribute__((address_space(1))) void*)gb,
                                       (__attribute__((address_space(3))) void*)lb, 16, 0, 0);
    }
    __syncthreads();
    bf16x8 af[4], bfv[4];
#pragma unroll
    for (int mi = 0; mi < 4; mi++)
      af[mi] = *(const bf16x8*)&As[(wm * 64 + mi * 16 + mrow) * 32 + quad * 8];
#pragma unroll
    for (int ni = 0; ni < 4; ni++)
      bfv[ni] = *(const bf16x8*)&Bs[(wn * 64 + ni * 16 + mrow) * 32 + quad * 8];
#pragma unroll
    for (int mi = 0; mi < 4; mi++)
#pragma unroll
      for (int ni = 0; ni < 4; ni++)
        acc[mi][ni] = __builtin_amdgcn_mfma_f32_16x16x32_bf16(af[mi], bfv[ni], acc[mi][ni], 0, 0, 0);
  }

#pragma unroll
  for (int mi = 0; mi < 4; mi++)
#pragma unroll
    for (int ni = 0; ni < 4; ni++) {
      int col = n0 + wn * 64 + ni * 16 + mrow;
      float bv2 = bias[col];
      if (widx < 2) {
        short* outb = widx ? Kb : Qb;
#pragma unroll
        for (int r = 0; r < 4; r++) {
          int row = m0 + wm * 64 + mi * 16 + quad * 4 + r;
          outb[(size_t)row * 512 + col] = f2bf((acc[mi][ni][r] + bv2) * qscale);
        }
      } else {
        int row0 = m0 + wm * 64 + mi * 16 + quad * 4;
        int b = row0 >> 12, t0 = row0 & 4095;
        short4 o;
        o.x = f2bf(acc[mi][ni][0] + bv2);
        o.y = f2bf(acc[mi][ni][1] + bv2);
        o.z = f2bf(acc[mi][ni][2] + bv2);
        o.w = f2bf(acc[mi][ni][3] + bv2);
        *(short4*)&Vt[(size_t)b * (512 * 4096) + (size_t)col * 4096 + t0] = o;
      }
    }
}

// ---------- GEMM (final projection, validated) ----------
__global__ __launch_bounds__(256) void gemm_k(const short* __restrict__ A,
                                              const short* __restrict__ Bt,
                                              const float* __restrict__ bias,
                                              const float* __restrict__ xres,
                                              float* __restrict__ outf) {
  __shared__ __attribute__((aligned(16))) short As[128 * 32];
  __shared__ __attribute__((aligned(16))) short Bs[128 * 32];
  int tid = threadIdx.x;
  int w = tid >> 6, lane = tid & 63, quad = lane >> 4, mrow = lane & 15;
  int wm = w >> 1, wn = w & 1;
  int m0 = blockIdx.x * 128, n0 = blockIdx.y * 128;

  const f32x4 fz = {0.f, 0.f, 0.f, 0.f};
  f32x4 acc[4][4];
#pragma unroll
  for (int i = 0; i < 4; i++)
#pragma unroll
    for (int j = 0; j < 4; j++) acc[i][j] = fz;

  int srow = tid >> 2;
  int scol = (tid & 3) * 8;

  for (int k0 = 0; k0 < 512; k0 += 32) {
    __syncthreads();
#pragma unroll
    for (int i = 0; i < 2; i++) {
      const short* ga = A + (size_t)(m0 + i * 64 + srow) * 512 + k0 + scol;
      const short* gb = Bt + (size_t)(n0 + i * 64 + srow) * 512 + k0 + scol;
      char* la = (char*)As + i * 4096 + w * 1024;
      char* lb = (char*)Bs + i * 4096 + w * 1024;
      __builtin_amdgcn_global_load_lds((__attribute__((address_space(1))) void*)ga,
                                       (__attribute__((address_space(3))) void*)la, 16, 0, 0);
      __builtin_amdgcn_global_load_lds((__attribute__((address_space(1))) void*)gb,
                                       (__attribute__((address_space(3))) void*)lb, 16, 0, 0);
    }
    __syncthreads();
    bf16x8 af[4], bfv[4];
#pragma unroll
    for (int mi = 0; mi < 4; mi++)
      af[mi] = *(const bf16x8*)&As[(wm * 64 + mi * 16 + mrow) * 32 + quad * 8];
#pragma unroll
    for (int ni = 0; ni < 4; ni++)
      bfv[ni] = *(const bf16x8*)&Bs[(wn * 64 + ni * 16 + mrow) * 32 + quad * 8];
#pragma unroll
    for (int mi = 0; mi < 4; mi++)
#pragma unroll
      for (int ni = 0; ni < 4; ni++)
        acc[mi][ni] = __builtin_amdgcn_mfma_f32_16x16x32_bf16(af[mi], bfv[ni], acc[mi][ni], 0, 0, 0);
  }

#pragma unroll
  for (int mi = 0; mi < 4; mi++)
#pragma unroll
    for (int ni = 0; ni < 4; ni++) {
      int col = n0 + wn * 64 + ni * 16 + mrow;
      float bv = bias[col];
#pragma unroll
      for (int r = 0; r < 4; r++) {
        int row = m0 + wm * 64 + mi * 16 + quad * 4 + r;
        size_t idx = (size_t)row * 512 + col;
        outf[idx] = xres[idx] + acc[mi][ni][r] + bv;
      }
    }
}

// ---------- flash attention v15: v13 registers + v14 scheduling (barrier at END) ----------
// v14 spilled (WRITE 33MB): next-iter S partials + double-V = 270 VGPR live.
// v15 keeps v13's state (single vr consumed same body; s0/s1 die at Sx write
// BEFORE the barrier) but moves the barrier to body END so the two chains
//   A: QK(it+1) [ds_read Ks + MFMA] -> Sx write(it+1)
//   B: Sx read(it) -> softmax(it) -> pack -> PV(it)
// are both inside one barrier interval and independent -> VALU softmax hides
// under matrix-pipe QK. Peak live ~ qf64+oacc64+vr32+s0s1(32)+pl16+tmp ~ 240.
// 2 QK chains (v12-validated) for headroom. No templates/reference arrays.
// Uniform body it=0..126 (staging guarded it<126: K(128) is OOB), it=127
// peeled (no QK/staging/SxWrite/barrier -> no conditional MFMA state).
// vmcnt(0) at the end barrier is ~free: staging had a full body; V already
// waited at PV. Riders: pack shuffle-halving (pre-select Z=hi?A:C so ONE
// shfl_xor serves both words; 8->4 shfl/iter), tree max/sum reductions.
__device__ __forceinline__ f32x16 qkmfma(bf16x8 a, bf16x8 b, f32x16 c) {
  return __builtin_amdgcn_mfma_f32_32x32x16_bf16(a, b, c, 0, 0, 0);
}

__global__ __launch_bounds__(512, 2) void flash_k(const short* __restrict__ Q,
                                                  const short* __restrict__ K,
                                                  const short* __restrict__ Vt,
                                                  short* __restrict__ O) {
  __shared__ __attribute__((aligned(16))) short Ks[2][16384];   // 64 KB
  __shared__ __attribute__((aligned(16))) float Sx[2][8192];    // 64 KB exchange (dbuf)
  int L = blockIdx.x;
  int b = (L & 7) >> 1;                       // batch -> XCD pair (L%8 round-robin)
  int q0 = (((L >> 3) << 1) | (L & 1)) * 64;
  int tid = threadIdx.x;
  int w = tid >> 6, lane = tid & 63;
  int ql = lane & 31, hi = lane >> 5;
  int qh = w & 1;                             // query half (32 queries)
  int gg = w >> 1;                            // PV channel quarter (128 ch)
  int kj = gg & 1;                            // QK k-split half (256 ch)
  const size_t batch_off = (size_t)b * 4096 * 512;

  // Q fragments (B-operand 32x32x16: col=query=ql, k=hi*8+j); Q pre-scaled
  const short* Qrow = Q + batch_off + (size_t)(q0 + qh * 32 + ql) * 512 + kj * 256;
  bf16x8 qf[16];
#pragma unroll
  for (int s = 0; s < 16; s++)
    qf[s] = *(const bf16x8*)&Qrow[s * 16 + hi * 8];

  const f32x16 fz16 = {0,0,0,0,0,0,0,0,0,0,0,0,0,0,0,0};
  f32x16 oacc[4];
#pragma unroll
  for (int i = 0; i < 4; i++) oacc[i] = fz16;
  float mrun = -1e30f, lrun = 0.f;

  const short* Vb0 = Vt + batch_off + (size_t)(gg * 128 + ql) * 4096 + hi * 8;

  // ---- prologue: stage K(0); drain; stage K(1); QK(0); Sx[0] write; barrier ----
#pragma unroll
  for (int i = 0; i < 4; i++) {
    int s = w * 4 + i;
    const short* gk = K + batch_off + (size_t)ql * 512 + s * 16 + hi * 8;
    __builtin_amdgcn_global_load_lds((__attribute__((address_space(1))) void*)gk,
                                     (__attribute__((address_space(3))) void*)&Ks[0][s * 512],
                                     16, 0, 0);
  }
  __syncthreads();                            // K(0) ready
#pragma unroll
  for (int i = 0; i < 4; i++) {
    int s = w * 4 + i;
    const short* gk = K + batch_off + (size_t)(32 + ql) * 512 + s * 16 + hi * 8;
    __builtin_amdgcn_global_load_lds((__attribute__((address_space(1))) void*)gk,
                                     (__attribute__((address_space(3))) void*)&Ks[1][s * 512],
                                     16, 0, 0);
  }
  {
    f32x16 s0 = fz16, s1 = fz16;
#pragma unroll
    for (int s = 0; s < 16; s += 2) {
      bf16x8 k0 = *(const bf16x8*)&Ks[0][(kj * 16 + s + 0) * 512 + lane * 8];
      bf16x8 k1 = *(const bf16x8*)&Ks[0][(kj * 16 + s + 1) * 512 + lane * 8];
      s0 = qkmfma(k0, qf[s + 0], s0);
      s1 = qkmfma(k1, qf[s + 1], s1);
    }
#pragma unroll
    for (int i = 0; i < 4; i++) {
      f32x4 cc;
      cc[0] = s0[4 * i + 0] + s1[4 * i + 0];
      cc[1] = s0[4 * i + 1] + s1[4 * i + 1];
      cc[2] = s0[4 * i + 2] + s1[4 * i + 2];
      cc[3] = s0[4 * i + 3] + s1[4 * i + 3];
      *(f32x4*)&Sx[0][w * 1024 + i * 256 + lane * 4] = cc;
    }
  }
  asm volatile("s_waitcnt lgkmcnt(0) vmcnt(0)" ::: "memory");   // Sx(0) + K(1) ready
  __builtin_amdgcn_s_barrier();
  asm volatile("" ::: "memory");

  // ---- main loop: ONE barrier per iter, at body END ----
#pragma unroll 1
  for (int it = 0; it < 127; ++it) {
    int buf = it & 1;
    int t0 = it * 32;
    // 1. stage K(it+2) -> Ks[buf] (last read pre-barrier(it-1); K(128) OOB-guarded)
    if (it < 126) {
#pragma unroll
      for (int i = 0; i < 4; i++) {
        int s = w * 4 + i;
        const short* gk = K + batch_off + (size_t)(t0 + 64 + ql) * 512 + s * 16 + hi * 8;
        __builtin_amdgcn_global_load_lds((__attribute__((address_space(1))) void*)gk,
                                         (__attribute__((address_space(3))) void*)&Ks[buf][s * 512],
                                         16, 0, 0);
      }
    }
    // 2. V(it) -> registers (consumed at PV this body; long latency window)
    bf16x8 vr[4][2];
#pragma unroll
    for (int cb = 0; cb < 4; cb++) {
      vr[cb][0] = *(const bf16x8*)(Vb0 + (size_t)cb * 131072 + t0);
      vr[cb][1] = *(const bf16x8*)(Vb0 + (size_t)cb * 131072 + t0 + 16);
    }
    // 3. Sx read(it): own + partner partials (issue before QK ds_reads)
    float pl[16];
#pragma unroll
    for (int i = 0; i < 4; i++) {
      f32x4 a = *(const f32x4*)&Sx[buf][w * 1024 + i * 256 + lane * 4];
      f32x4 d = *(const f32x4*)&Sx[buf][(w ^ 2) * 1024 + i * 256 + lane * 4];
      pl[4 * i + 0] = a[0] + d[0];
      pl[4 * i + 1] = a[1] + d[1];
      pl[4 * i + 2] = a[2] + d[2];
      pl[4 * i + 3] = a[3] + d[3];
    }
    // 4. QK(it+1) from Ks[buf^1]: independent MFMA chain (overlaps softmax VALU)
    f32x16 s0 = fz16, s1 = fz16;
#pragma unroll
    for (int s = 0; s < 16; s += 2) {
      bf16x8 k0 = *(const bf16x8*)&Ks[buf ^ 1][(kj * 16 + s + 0) * 512 + lane * 8];
      bf16x8 k1 = *(const bf16x8*)&Ks[buf ^ 1][(kj * 16 + s + 1) * 512 + lane * 8];
      s0 = qkmfma(k0, qf[s + 0], s0);
      s1 = qkmfma(k1, qf[s + 1], s1);
    }
    // 5. softmax(it): tree max, defer-max, exp2, tree sum
    float tm[8];
#pragma unroll
    for (int r = 0; r < 8; r++) tm[r] = fmaxf(pl[r], pl[r + 8]);
    float mx = fmaxf(fmaxf(fmaxf(tm[0], tm[1]), fmaxf(tm[2], tm[3])),
                     fmaxf(fmaxf(tm[4], tm[5]), fmaxf(tm[6], tm[7])));
    mx = fmaxf(mx, __shfl_xor(mx, 32, 64));
    if (__any(mx > mrun + 8.0f)) {            // defer-max (THR=8, validated)
      float mn = fmaxf(mrun, mx);
      float alpha = exp2f(mrun - mn);
      mrun = mn;
      lrun *= alpha;
      float al[16];
#pragma unroll
      for (int r = 0; r < 16; r++)
        al[r] = __shfl(alpha, (r & 3) + 8 * (r >> 2) + 4 * hi, 64);
#pragma unroll
      for (int cb = 0; cb < 4; cb++)
#pragma unroll
        for (int r = 0; r < 16; r++) oacc[cb][r] *= al[r];
    }
    float p[16];
#pragma unroll
    for (int r = 0; r < 16; r++) p[r] = exp2f(pl[r] - mrun);
    float ts[8];
#pragma unroll
    for (int r = 0; r < 8; r++) ts[r] = p[r] + p[r + 8];
    float sum = ((ts[0] + ts[1]) + (ts[2] + ts[3])) + ((ts[4] + ts[5]) + (ts[6] + ts[7]));
    sum += __shfl_xor(sum, 32, 64);
    lrun += sum;
    // 6. pack P -> A-frags (cvt_pk + HALved shuffle count)
    bf16x8 af0, af1;
#pragma unroll
    for (int ks = 0; ks < 2; ks++) {
      uint32_t Aw, Bw, Cw, Dw;
      asm("v_cvt_pk_bf16_f32 %0, %1, %2" : "=v"(Aw) : "v"(p[8 * ks + 0]), "v"(p[8 * ks + 1]));
      asm("v_cvt_pk_bf16_f32 %0, %1, %2" : "=v"(Bw) : "v"(p[8 * ks + 2]), "v"(p[8 * ks + 3]));
      asm("v_cvt_pk_bf16_f32 %0, %1, %2" : "=v"(Cw) : "v"(p[8 * ks + 4]), "v"(p[8 * ks + 5]));
      asm("v_cvt_pk_bf16_f32 %0, %1, %2" : "=v"(Dw) : "v"(p[8 * ks + 6]), "v"(p[8 * ks + 7]));
      uint32_t Zac = hi ? Aw : Cw;            // pre-select: one swap serves both words
      uint32_t Zbd = hi ? Bw : Dw;
      uint32_t Sac = (uint32_t)__shfl_xor((int)Zac, 32, 64);
      uint32_t Sbd = (uint32_t)__shfl_xor((int)Zbd, 32, 64);
      u32x4 u;
      u[0] = hi ? Sac : Aw;                   // == hi?Csw:Aw  (v13-validated mapping)
      u[1] = hi ? Sbd : Bw;                   // == hi?Dsw:Bw
      u[2] = hi ? Cw : Sac;                   // == hi?Cw:Asw
      u[3] = hi ? Dw : Sbd;                   // == hi?Dw:Bsw
      if (ks == 0) af0 = __builtin_bit_cast(bf16x8, u);
      else         af1 = __builtin_bit_cast(bf16x8, u);
    }
    // 7. PV(it)
#pragma unroll
    for (int cb = 0; cb < 4; cb++) {
      oacc[cb] = qkmfma(af0, vr[cb][0], oacc[cb]);
      oacc[cb] = qkmfma(af1, vr[cb][1], oacc[cb]);
    }
    // 8. Sx write(it+1) -> Sx[buf^1]
#pragma unroll
    for (int i = 0; i < 4; i++) {
      f32x4 cc;
      cc[0] = s0[4 * i + 0] + s1[4 * i + 0];
      cc[1] = s0[4 * i + 1] + s1[4 * i + 1];
      cc[2] = s0[4 * i + 2] + s1[4 * i + 2];
      cc[3] = s0[4 * i + 3] + s1[4 * i + 3];
      *(f32x4*)&Sx[buf ^ 1][w * 1024 + i * 256 + lane * 4] = cc;
    }
    // 9. end-of-body barrier: Sx(it+1) visible, K(it+2) staged (vmcnt free)
    asm volatile("s_waitcnt lgkmcnt(0) vmcnt(0)" ::: "memory");
    __builtin_amdgcn_s_barrier();
    asm volatile("" ::: "memory");
  }
  // ---- peeled final iteration (it=127): no QK/staging/SxWrite/barrier ----
  {
    const int it = 127, buf = it & 1;
    int t0 = it * 32;
    bf16x8 vr[4][2];
#pragma unroll
    for (int cb = 0; cb < 4; cb++) {
      vr[cb][0] = *(const bf16x8*)(Vb0 + (size_t)cb * 131072 + t0);
      vr[cb][1] = *(const bf16x8*)(Vb0 + (size_t)cb * 131072 + t0 + 16);
    }
    float pl[16];
#pragma unroll
    for (int i = 0; i < 4; i++) {
      f32x4 a = *(const f32x4*)&Sx[buf][w * 1024 + i * 256 + lane * 4];
      f32x4 d = *(const f32x4*)&Sx[buf][(w ^ 2) * 1024 + i * 256 + lane * 4];
      pl[4 * i + 0] = a[0] + d[0];
      pl[4 * i + 1] = a[1] + d[1];
      pl[4 * i + 2] = a[2] + d[2];
      pl[4 * i + 3] = a[3] + d[3];
    }
    float tm[8];
#pragma unroll
    for (int r = 0; r < 8; r++) tm[r] = fmaxf(pl[r], pl[r + 8]);
    float mx = fmaxf(fmaxf(fmaxf(tm[0], tm[1]), fmaxf(tm[2], tm[3])),
                     fmaxf(fmaxf(tm[4], tm[5]), fmaxf(tm[6], tm[7])));
    mx = fmaxf(mx, __shfl_xor(mx, 32, 64));
    if (__any(mx > mrun + 8.0f)) {
      float mn = fmaxf(mrun, mx);
      float alpha = exp2f(mrun - mn);
      mrun = mn;
      lrun *= alpha;
      float al[16];
#pragma unroll
      for (int r = 0; r < 16; r++)
        al[r] = __shfl(alpha, (r & 3) + 8 * (r >> 2) + 4 * hi, 64);
#pragma unroll
      for (int cb = 0; cb < 4; cb++)
#pragma unroll
        for (int r = 0; r < 16; r++) oacc[cb][r] *= al[r];
    }
    float p[16];
#pragma unroll
    for (int r = 0; r < 16; r++) p[r] = exp2f(pl[r] - mrun);
    float ts[8];
#pragma unroll
    for (int r = 0; r < 8; r++) ts[r] = p[r] + p[r + 8];
    float sum = ((ts[0] + ts[1]) + (ts[2] + ts[3])) + ((ts[4] + ts[5]) + (ts[6] + ts[7]));
    sum += __shfl_xor(sum, 32, 64);
    lrun += sum;
    bf16x8 af0, af1;
#pragma unroll
    for (int ks = 0; ks < 2; ks++) {
      uint32_t Aw, Bw, Cw, Dw;
      asm("v_cvt_pk_bf16_f32 %0, %1, %2" : "=v"(Aw) : "v"(p[8 * ks + 0]), "v"(p[8 * ks + 1]));
      asm("v_cvt_pk_bf16_f32 %0, %1, %2" : "=v"(Bw) : "v"(p[8 * ks + 2]), "v"(p[8 * ks + 3]));
      asm("v_cvt_pk_bf16_f32 %0, %1, %2" : "=v"(Cw) : "v"(p[8 * ks + 4]), "v"(p[8 * ks + 5]));
      asm("v_cvt_pk_bf16_f32 %0, %1, %2" : "=v"(Dw) : "v"(p[8 * ks + 6]), "v"(p[8 * ks + 7]));
      uint32_t Zac = hi ? Aw : Cw;
      uint32_t Zbd = hi ? Bw : Dw;
      uint32_t Sac = (uint32_t)__shfl_xor((int)Zac, 32, 64);
      uint32_t Sbd = (uint32_t)__shfl_xor((int)Zbd, 32, 64);
      u32x4 u;
      u[0] = hi ? Sac : Aw;
      u[1] = hi ? Sbd : Bw;
      u[2] = hi ? Cw : Sac;
      u[3] = hi ? Dw : Sbd;
      if (ks == 0) af0 = __builtin_bit_cast(bf16x8, u);
      else         af1 = __builtin_bit_cast(bf16x8, u);
    }
#pragma unroll
    for (int cb = 0; cb < 4; cb++) {
      oacc[cb] = qkmfma(af0, vr[cb][0], oacc[cb]);
      oacc[cb] = qkmfma(af1, vr[cb][1], oacc[cb]);
    }
  }
  // ---- epilogue: O /= l, store bf16 row-major (rows=queries crow(r,hi)) ----
  float invl = 1.f / lrun;
  float ir[16];
#pragma unroll
  for (int r = 0; r < 16; r++)
    ir[r] = __shfl(invl, (r & 3) + 8 * (r >> 2) + 4 * hi, 64);
#pragma unroll
  for (int cb = 0; cb < 4; cb++) {
    int col = gg * 128 + cb * 32 + ql;
#pragma unroll
    for (int r = 0; r < 16; r++) {
      int row = q0 + qh * 32 + (r & 3) + 8 * (r >> 2) + 4 * hi;
      O[batch_off + (size_t)row * 512 + col] = f2bf(oacc[cb][r] * ir[r]);
    }
  }
}

extern "C" void kernel_launch(void* const* d_in, const int* in_sizes, int n_in,
                              void* d_out, int out_size, void* d_ws, size_t ws_size,
                              hipStream_t stream) {
  const float* x  = (const float*)d_in[0];
  const float* gs = (const float*)d_in[1];
  const float* gb = (const float*)d_in[2];
  const float* wq = (const float*)d_in[3];
  const float* bq = (const float*)d_in[4];
  const float* wk = (const float*)d_in[5];
  const float* bk = (const float*)d_in[6];
  const float* wv = (const float*)d_in[7];
  const float* bv = (const float*)d_in[8];
  const float* wp = (const float*)d_in[9];
  const float* bp = (const float*)d_in[10];
  float* out = (float*)d_out;

  // ---- workspace layout (~35.7 MB; Q/K live in d_out until final GEMM) ----
  char* ws = (char*)d_ws;
  float2* sums = (float2*)ws;                             // 256 float2 (2 KB)
  short* h    = (short*)(ws + 4096);                      // 16384*512 bf16 (16.78 MB)
  short* wt   = (short*)(ws + 4096 + 16777216);           // 4*512*512 bf16 (2 MB)
  short* Vt   = (short*)(ws + 4096 + 16777216 + 2097152); // [b][c][t] bf16 (16.78 MB)
  short* Qb   = (short*)d_out;                            // 16.78 MB in d_out
  short* Kb   = Qb + 8388608;                             // 16.78 MB in d_out
  short* Ob   = h;                                        // alias: h dead after V GEMM

  gn_stats_k<<<256, 256, 0, stream>>>(x, sums);
  gn_apply_k<<<8192, 256, 0, stream>>>(x, sums, gs, gb, h);
  wconv_k<<<4096, 256, 0, stream>>>(wq, wk, wv, wp, wt);
  qkv_gemm_k<<<dim3(128, 12), 256, 0, stream>>>(h, wt, bq, bk, bv, Qb, Kb, Vt);
  flash_k<<<256, 512, 0, stream>>>(Qb, Kb, Vt, Ob);
  // final projection reads Ob (=h space), x, wt_p; writes d_out (overwrites Q/K)
  gemm_k<<<dim3(128, 4), 256, 0, stream>>>(Ob, wt + 786432, bp, x, out);
}